// Round 2
// baseline (355.465 us; speedup 1.0000x reference)
//
#include <hip/hip_runtime.h>

// Problem constants (from reference): x is (B=32, NC=64, H=128, W=128) fp32.
// out[b,j,hw] = exp( sum_i log(relu(x[b,i,hw])+0.1) * E[i,j] ) + bias[j]
#define NCH 64
#define HWSZ 16384   // 128*128
#define NPOINTS (32 * HWSZ)  // B * H * W = 524288

// __launch_bounds__(256, 2): R1's (256)-only let the allocator target high
// occupancy -> 56 VGPRs -> acc[64] spilled to scratch -> 3x WRITE_SIZE and
// 187 us. Min-2-waves/EU permits up to 256 VGPRs; actual ~100 -> no spill.
__global__ __launch_bounds__(256, 2) void fused_log_einsum_exp(
    const float* __restrict__ x,
    const float* __restrict__ E,     // (64,64) row-major: E[i*64+j]
    const float* __restrict__ bias,  // (64)
    float* __restrict__ out)
{
    __shared__ float Es[NCH * NCH];   // 16 KiB
    __shared__ float bs[NCH];

    // Cooperative load of E: 4096 floats / 256 threads = 16 each, coalesced.
    #pragma unroll
    for (int k = 0; k < 16; ++k)
        Es[k * 256 + threadIdx.x] = E[k * 256 + threadIdx.x];
    if (threadIdx.x < NCH) bs[threadIdx.x] = bias[threadIdx.x];
    __syncthreads();

    const int p  = blockIdx.x * 256 + threadIdx.x;  // one spatial point/thread
    const int b  = p >> 14;          // p / HWSZ
    const int hw = p & (HWSZ - 1);   // p % HWSZ

    const float* xp = x   + (size_t)b * NCH * HWSZ + hw;
    float*       op = out + (size_t)b * NCH * HWSZ + hw;

    float acc[NCH];
    #pragma unroll
    for (int j = 0; j < NCH; ++j) acc[j] = 0.0f;

    // Stream input channels; each x element is loaded (coalesced) and logged
    // exactly once. E row reads are wave-uniform -> LDS broadcast (ds_read_b128).
    #pragma unroll 2
    for (int i = 0; i < NCH; ++i) {
        float v  = xp[(size_t)i * HWSZ];
        float lx = __logf(fmaxf(v, 0.0f) + 0.1f);
        #pragma unroll
        for (int j = 0; j < NCH; ++j)
            acc[j] = fmaf(lx, Es[i * NCH + j], acc[j]);
    }

    // Epilogue: exp + bias, coalesced stores per output channel.
    #pragma unroll 4
    for (int j = 0; j < NCH; ++j)
        op[(size_t)j * HWSZ] = __expf(acc[j]) + bs[j];
}

extern "C" void kernel_launch(void* const* d_in, const int* in_sizes, int n_in,
                              void* d_out, int out_size, void* d_ws, size_t ws_size,
                              hipStream_t stream) {
    const float* x    = (const float*)d_in[0];
    const float* E    = (const float*)d_in[1];   // (64,64,1,1) -> [i*64+j]
    const float* bias = (const float*)d_in[2];   // (64,1,1)
    float* out = (float*)d_out;

    dim3 grid(NPOINTS / 256), block(256);
    hipLaunchKernelGGL(fused_log_einsum_exp, grid, block, 0, stream,
                       x, E, bias, out);
}

// Round 3
// 307.277 us; speedup vs baseline: 1.1568x; 1.1568x over previous
//
#include <hip/hip_runtime.h>

// Problem constants (from reference): x is (B=32, NC=64, H=128, W=128) fp32.
// out[b,j,hw] = exp( sum_i log(relu(x[b,i,hw])+0.1) * E[i,j] ) + bias[j]
#define NCH 64
#define HWSZ 16384   // 128*128
#define NPOINTS (32 * HWSZ)  // B * H * W = 524288

// CRITICAL: every acc[] access must use a compile-time index (full unroll on
// all j loops). R1/R2 used `#pragma unroll 4` on the epilogue -> dynamic
// index -> SROA blocked -> acc[64] lived in scratch -> 4096 scratch RMWs per
// thread -> +250 MB HBM writes, 203 us. VGPR_Count must read ~110+, not ~68.
__global__ __launch_bounds__(256, 2) void fused_log_einsum_exp(
    const float* __restrict__ x,
    const float* __restrict__ E,     // (64,64) row-major: E[i*64+j]
    const float* __restrict__ bias,  // (64)
    float* __restrict__ out)
{
    __shared__ float Es[NCH * NCH];   // 16 KiB
    __shared__ float bs[NCH];

    // Cooperative load of E: 4096 floats / 256 threads = 16 each, coalesced.
    #pragma unroll
    for (int k = 0; k < 16; ++k)
        Es[k * 256 + threadIdx.x] = E[k * 256 + threadIdx.x];
    if (threadIdx.x < NCH) bs[threadIdx.x] = bias[threadIdx.x];
    __syncthreads();

    const int p  = blockIdx.x * 256 + threadIdx.x;  // one spatial point/thread
    const int b  = p >> 14;          // p / HWSZ
    const int hw = p & (HWSZ - 1);   // p % HWSZ

    const float* xp = x   + (size_t)b * NCH * HWSZ + hw;
    float*       op = out + (size_t)b * NCH * HWSZ + hw;

    float acc[NCH];
    #pragma unroll
    for (int j = 0; j < NCH; ++j) acc[j] = 0.0f;   // full unroll: static idx

    // Stream input channels; each x element loaded (coalesced) + logged once.
    // E row reads are wave-uniform -> LDS broadcast ds_read_b128.
    // i stays a runtime loop (only Es/LDS is dynamically indexed — legal);
    // unroll 2 to overlap the next global load with current FMAs.
    #pragma unroll 2
    for (int i = 0; i < NCH; ++i) {
        float v  = xp[(size_t)i * HWSZ];
        float lx = __logf(fmaxf(v, 0.0f) + 0.1f);
        #pragma unroll
        for (int j = 0; j < NCH; ++j)              // full unroll: static idx
            acc[j] = fmaf(lx, Es[i * NCH + j], acc[j]);
    }

    // Epilogue: exp + bias, coalesced stores per output channel.
    #pragma unroll
    for (int j = 0; j < NCH; ++j)                  // FULL unroll (the R1/R2 bug)
        op[(size_t)j * HWSZ] = __expf(acc[j]) + bs[j];
}

extern "C" void kernel_launch(void* const* d_in, const int* in_sizes, int n_in,
                              void* d_out, int out_size, void* d_ws, size_t ws_size,
                              hipStream_t stream) {
    const float* x    = (const float*)d_in[0];
    const float* E    = (const float*)d_in[1];   // (64,64,1,1) -> [i*64+j]
    const float* bias = (const float*)d_in[2];   // (64,1,1)
    float* out = (float*)d_out;

    dim3 grid(NPOINTS / 256), block(256);
    hipLaunchKernelGGL(fused_log_einsum_exp, grid, block, 0, stream,
                       x, E, bias, out);
}

// Round 4
// 256.090 us; speedup vs baseline: 1.3880x; 1.1999x over previous
//
#include <hip/hip_runtime.h>

// out[b,j,hw] = exp( sum_i log(relu(x[b,i,hw])+0.1) * E[i,j] ) + bias[j]
// x: (B=32, NC=64, H=128, W=128) fp32.
#define NCH 64
#define HWSZ 16384   // 128*128
#define NPOINTS (32 * HWSZ)  // B * H * W = 524288

// R3 was LDS-throughput-bound: 16 ds_read_b128 per i per wave for the E row
// (8.4M total, ~12cyc each -> 164 us predicted, 155 measured). Fix: no LDS at
// all. E reads are wave-uniform + invariant (__restrict__, read-only) -> the
// AMDGPU backend converts them to s_load_dwordx* into SGPRs; the inner loop
// becomes v_fmac_f32 vacc, s_e, v_lx on the VALU pipe alone (~27 us), under
// the ~43 us HBM floor. Tell that it worked: SGPR_Count ~90+, LDS=0.
__global__ __launch_bounds__(256, 2) void fused_log_einsum_exp(
    const float* __restrict__ x,
    const float* __restrict__ E,     // (64,64) row-major: E[i*64+j]
    const float* __restrict__ bias,  // (64)
    float* __restrict__ out)
{
    const int p  = blockIdx.x * 256 + threadIdx.x;  // one spatial point/thread
    const int b  = p >> 14;          // p / HWSZ
    const int hw = p & (HWSZ - 1);   // p % HWSZ

    const float* xp = x   + (size_t)b * NCH * HWSZ + hw;
    float*       op = out + (size_t)b * NCH * HWSZ + hw;

    float acc[NCH];
    #pragma unroll
    for (int j = 0; j < NCH; ++j) acc[j] = 0.0f;   // static idx only (SROA)

    // Stream input channels: coalesced 256B/wave x-load, one log per element.
    // E[i*64+j]: i is a uniform loop counter, j a compile-time constant ->
    // uniform invariant address -> SMEM (s_load) expected.
    #pragma unroll 4
    for (int i = 0; i < NCH; ++i) {
        float v  = xp[(size_t)i * HWSZ];
        float lx = __logf(fmaxf(v, 0.0f) + 0.1f);
        #pragma unroll
        for (int j = 0; j < NCH; ++j)
            acc[j] = fmaf(lx, E[i * NCH + j], acc[j]);
    }

    // Epilogue: exp + bias (uniform -> SMEM), coalesced stores per channel.
    #pragma unroll
    for (int j = 0; j < NCH; ++j)
        op[(size_t)j * HWSZ] = __expf(acc[j]) + bias[j];
}

extern "C" void kernel_launch(void* const* d_in, const int* in_sizes, int n_in,
                              void* d_out, int out_size, void* d_ws, size_t ws_size,
                              hipStream_t stream) {
    const float* x    = (const float*)d_in[0];
    const float* E    = (const float*)d_in[1];   // (64,64,1,1) -> [i*64+j]
    const float* bias = (const float*)d_in[2];   // (64,1,1)
    float* out = (float*)d_out;

    dim3 grid(NPOINTS / 256), block(256);
    hipLaunchKernelGGL(fused_log_einsum_exp, grid, block, 0, stream,
                       x, E, bias, out);
}